// Round 1
// baseline (101.626 us; speedup 1.0000x reference)
//
#include <hip/hip_runtime.h>
#include <hip/hip_bf16.h>

// ---------------------------------------------------------------------------
// ContrastiveLoss: B=8192, D=64, fp32 inputs, scalar fp32 output.
// loss = mean_i[ w_i * (-(d_i - lse_row_i) - (d_i - lse_col_i)) ] / 2
//   w_i = (1 - exp(d_i - lse_row_i))^2,  d_i = (img_i . txt_i)/T (fp32 exact)
//   lse_row_i = M + ln( sum_j exp(s_ij - M) ),  M = 1/T  (fixed shift: |s|<=M)
// ---------------------------------------------------------------------------

#define NB 8192
#define ND 64

constexpr float INV_T = 1.0f / 0.07f;                 // 14.2857...
constexpr float LOG2E = 1.4426950408889634f;
constexpr float LN2   = 0.6931471805599453f;
constexpr float K1    = INV_T * LOG2E;                // exp2 arg scale

typedef float  floatx4 __attribute__((ext_vector_type(4)));
typedef short  bf16x8  __attribute__((ext_vector_type(8)));

// --------------------------- kernel 1: normalize ---------------------------
// One wave per row (D=64 == wave width). Normalize img and txt rows in fp32,
// emit bf16 copies for MFMA and the exact fp32 diagonal logit d_i * (1/T).
__global__ __launch_bounds__(256)
void norm_kernel(const float* __restrict__ img, const float* __restrict__ txt,
                 __hip_bfloat16* __restrict__ imgB,
                 __hip_bfloat16* __restrict__ txtB,
                 float* __restrict__ diag)
{
    const int lane = threadIdx.x & 63;
    const int row  = blockIdx.x * 4 + (threadIdx.x >> 6);
    float x = img[row * ND + lane];
    float t = txt[row * ND + lane];
    float sx = x * x, st = t * t;
    #pragma unroll
    for (int o = 1; o < 64; o <<= 1) {
        sx += __shfl_xor(sx, o, 64);
        st += __shfl_xor(st, o, 64);
    }
    const float nx = x / fmaxf(sqrtf(sx), 1e-12f);
    const float nt = t / fmaxf(sqrtf(st), 1e-12f);
    float pd = nx * nt;
    #pragma unroll
    for (int o = 1; o < 64; o <<= 1) pd += __shfl_xor(pd, o, 64);
    imgB[row * ND + lane] = __float2bfloat16(nx);
    txtB[row * ND + lane] = __float2bfloat16(nt);
    if (lane == 0) diag[row] = pd * INV_T;
}

// ----------------------- kernel 2: streamed score pass ---------------------
// Wave w: strip = w>>5 (64 rows), chunk = w&31 (256 cols, 16 tiles of 16).
// A-fragments for the 4 row-tiles stay in registers across the whole j-loop.
// Per 16x16 tile: 2 MFMAs (K=64), exp2 on 4 acc values x 4 row-tiles,
// col partial (sum over the wave's 64 rows) -> unique-writer global store,
// row partials accumulate in registers, flushed once at the end.
// mfma_f32_16x16x32_bf16 layouts (HW-verified):
//   A: lane holds A[m=lane&15][k=(lane>>4)*8 + j], j=0..7  (8 contig bf16)
//   B: lane holds B[n=lane&15][k=(lane>>4)*8 + j]          (NT layout)
//   C/D: col = lane&15, row = (lane>>4)*4 + r
__global__ __launch_bounds__(256)
void score_kernel(const __hip_bfloat16* __restrict__ imgB,
                  const __hip_bfloat16* __restrict__ txtB,
                  float* __restrict__ rowPart,   // [32][8192]
                  float* __restrict__ colPart)   // [128][8192]
{
    const int wid   = threadIdx.x >> 6;
    const int lane  = threadIdx.x & 63;
    const int gw    = blockIdx.x * 4 + wid;   // 0..4095
    const int strip = gw >> 5;                // 0..127 -> rows strip*64..+63
    const int chunk = gw & 31;                // 0..31  -> cols chunk*256..+255
    const int m = lane & 15;
    const int q = lane >> 4;

    const bf16x8* __restrict__ A = (const bf16x8*)imgB;  // units of 8 elems
    const bf16x8* __restrict__ B = (const bf16x8*)txtB;

    const int rowbase = strip * 64;
    bf16x8 a[4][2];
    #pragma unroll
    for (int it = 0; it < 4; ++it) {
        const int r = rowbase + it * 16 + m;
        a[it][0] = A[r * 8 + q];        // k = q*8 .. q*8+7
        a[it][1] = A[r * 8 + 4 + q];    // k = 32 + q*8 ..
    }

    float rs[16];
    #pragma unroll
    for (int i = 0; i < 16; ++i) rs[i] = 0.f;

    for (int t = 0; t < 16; ++t) {
        const int n = chunk * 256 + t * 16 + m;   // this lane's column
        const bf16x8 b0 = B[n * 8 + q];
        const bf16x8 b1 = B[n * 8 + 4 + q];
        floatx4 acc[4];
        #pragma unroll
        for (int it = 0; it < 4; ++it) {
            floatx4 z = {0.f, 0.f, 0.f, 0.f};
            z = __builtin_amdgcn_mfma_f32_16x16x32_bf16(a[it][0], b0, z, 0, 0, 0);
            acc[it] = __builtin_amdgcn_mfma_f32_16x16x32_bf16(a[it][1], b1, z, 0, 0, 0);
        }
        float cs = 0.f;
        #pragma unroll
        for (int it = 0; it < 4; ++it) {
            #pragma unroll
            for (int r = 0; r < 4; ++r) {
                // exp(s - M) = exp2((dot - 1) * K1), s = dot/T, M = 1/T
                const float e = __builtin_amdgcn_exp2f((acc[it][r] - 1.0f) * K1);
                rs[it * 4 + r] += e;
                cs += e;
            }
        }
        // combine the 4 quads -> col sum over all 64 rows of the strip
        cs += __shfl_xor(cs, 16, 64);
        cs += __shfl_xor(cs, 32, 64);
        if (q == 0) colPart[strip * NB + n] = cs;   // unique writer
    }

    // flush row sums: reduce each rs[idx] across the 16 lanes of the quad
    #pragma unroll
    for (int idx = 0; idx < 16; ++idx) {
        float v = rs[idx];
        v += __shfl_xor(v, 1, 64);
        v += __shfl_xor(v, 2, 64);
        v += __shfl_xor(v, 4, 64);
        v += __shfl_xor(v, 8, 64);
        if (m == idx) {
            const int it = idx >> 2, r = idx & 3;
            rowPart[chunk * NB + rowbase + it * 16 + q * 4 + r] = v;  // unique writer
        }
    }
}

// --------------------------- kernel 3: finish ------------------------------
__global__ __launch_bounds__(256)
void finish_kernel(const float* __restrict__ rowPart,
                   const float* __restrict__ colPart,
                   const float* __restrict__ diag,
                   float* __restrict__ out)
{
    const int i = blockIdx.x * 256 + threadIdx.x;   // 0..8191
    float rowS = 0.f, colS = 0.f;
    #pragma unroll 4
    for (int c = 0; c < 32; ++c)  rowS += rowPart[c * NB + i];
    #pragma unroll 4
    for (int s = 0; s < 128; ++s) colS += colPart[s * NB + i];
    const float d     = diag[i];
    const float lse_r = INV_T + __builtin_amdgcn_logf(rowS) * LN2;
    const float lse_c = INV_T + __builtin_amdgcn_logf(colS) * LN2;
    const float lpr = d - lse_r;
    const float lpc = d - lse_c;
    const float p   = __builtin_amdgcn_exp2f(lpr * LOG2E);
    const float om  = 1.f - p;
    float contrib = om * om * (-lpr - lpc) * (0.5f / (float)NB);

    #pragma unroll
    for (int o = 1; o < 64; o <<= 1) contrib += __shfl_xor(contrib, o, 64);
    __shared__ float red[4];
    if ((threadIdx.x & 63) == 0) red[threadIdx.x >> 6] = contrib;
    __syncthreads();
    if (threadIdx.x == 0)
        atomicAdd(out, red[0] + red[1] + red[2] + red[3]);
}

// ---------------------------------------------------------------------------
extern "C" void kernel_launch(void* const* d_in, const int* in_sizes, int n_in,
                              void* d_out, int out_size, void* d_ws, size_t ws_size,
                              hipStream_t stream)
{
    const float* img = (const float*)d_in[0];
    const float* txt = (const float*)d_in[1];

    char* ws = (char*)d_ws;
    __hip_bfloat16* imgB = (__hip_bfloat16*)(ws);                        // 1 MB
    __hip_bfloat16* txtB = (__hip_bfloat16*)(ws + (1u << 20));           // 1 MB
    float* diag    = (float*)(ws + (2u << 20));                          // 32 KB
    float* rowPart = (float*)(ws + (2u << 20) + (1u << 16));             // 1 MB
    float* colPart = (float*)(ws + (3u << 20) + (1u << 16));             // 4 MB

    hipMemsetAsync(d_out, 0, sizeof(float), stream);   // d_out is re-poisoned

    norm_kernel<<<NB / 4, 256, 0, stream>>>(img, txt, imgB, txtB, diag);
    score_kernel<<<1024, 256, 0, stream>>>(imgB, txtB, rowPart, colPart);
    finish_kernel<<<NB / 256, 256, 0, stream>>>(rowPart, colPart, diag, (float*)d_out);
}

// Round 2
// 98.571 us; speedup vs baseline: 1.0310x; 1.0310x over previous
//
#include <hip/hip_runtime.h>
#include <hip/hip_bf16.h>

// ---------------------------------------------------------------------------
// ContrastiveLoss: B=8192, D=64, fp32 inputs, scalar fp32 output.
// loss = mean_i[ w_i * (-(d_i - lse_row_i) - (d_i - lse_col_i)) ] / 2
//   w_i = (1 - exp(d_i - lse_row_i))^2,  d_i = (img_i . txt_i)/T (fp32 exact)
//   lse_row_i = M + ln( sum_j exp(s_ij - M) ),  M = 1/T  (fixed shift: |s|<=M
//   since both factors are unit vectors -> no max pass needed)
// ---------------------------------------------------------------------------

#define NB 8192
#define ND 64

constexpr float INV_T = 1.0f / 0.07f;                 // 14.2857...
constexpr float LOG2E = 1.4426950408889634f;
constexpr float LN2   = 0.6931471805599453f;
constexpr float K1    = INV_T * LOG2E;                // exp2 arg scale

typedef float  floatx4 __attribute__((ext_vector_type(4)));
typedef short  bf16x8  __attribute__((ext_vector_type(8)));

// --------------------------- kernel 1: normalize ---------------------------
// One wave per row (D=64 == wave width). Single fused butterfly reduces
// |x|^2, |t|^2, x.t together; emits bf16 copies for MFMA and the exact fp32
// diagonal logit. Also zeroes d_out (runs strictly before finish_kernel).
__global__ __launch_bounds__(256)
void norm_kernel(const float* __restrict__ img, const float* __restrict__ txt,
                 __hip_bfloat16* __restrict__ imgB,
                 __hip_bfloat16* __restrict__ txtB,
                 float* __restrict__ diag,
                 float* __restrict__ out)
{
    if (blockIdx.x == 0 && threadIdx.x == 0) out[0] = 0.f;  // replaces memset node
    const int lane = threadIdx.x & 63;
    const int row  = blockIdx.x * 4 + (threadIdx.x >> 6);
    const float x = img[row * ND + lane];
    const float t = txt[row * ND + lane];
    float sx = x * x, st = t * t, sxt = x * t;
    #pragma unroll
    for (int o = 1; o < 64; o <<= 1) {
        sx  += __shfl_xor(sx,  o, 64);
        st  += __shfl_xor(st,  o, 64);
        sxt += __shfl_xor(sxt, o, 64);
    }
    const float nx_den = fmaxf(sqrtf(sx), 1e-12f);
    const float nt_den = fmaxf(sqrtf(st), 1e-12f);
    imgB[row * ND + lane] = __float2bfloat16(x / nx_den);
    txtB[row * ND + lane] = __float2bfloat16(t / nt_den);
    if (lane == 0) diag[row] = sxt / (nx_den * nt_den) * INV_T;
}

// ----------------------- kernel 2: streamed score pass ---------------------
// Wave w: strip = w>>5 (64 rows), chunk = w&31 (256 cols, 16 tiles of 16).
// A-fragments (4 row-tiles) stay in registers across the whole tile loop.
// Next tile's B-fragments are software-prefetched (branchless wraparound).
// Per 16x16 tile: 2 chained MFMAs (K=64) x 4 row-tiles, 16 exp2, row partial
// accumulation in registers, col partial via depth-4 tree + 2 shuffles.
// mfma_f32_16x16x32_bf16 layouts (HW-verified):
//   A: lane holds A[m=lane&15][k=(lane>>4)*8 + j], j=0..7  (8 contig bf16)
//   B: lane holds B[n=lane&15][k=(lane>>4)*8 + j]          (NT layout)
//   C/D: col = lane&15, row = (lane>>4)*4 + r
__global__ __launch_bounds__(256)
void score_kernel(const __hip_bfloat16* __restrict__ imgB,
                  const __hip_bfloat16* __restrict__ txtB,
                  float* __restrict__ rowPart,   // [32][8192]
                  float* __restrict__ colPart)   // [128][8192]
{
    const int wid   = threadIdx.x >> 6;
    const int lane  = threadIdx.x & 63;
    const int gw    = blockIdx.x * 4 + wid;   // 0..4095
    const int strip = gw >> 5;                // rows strip*64..+63
    const int chunk = gw & 31;                // cols chunk*256..+255
    const int m = lane & 15;
    const int q = lane >> 4;

    const bf16x8* __restrict__ A  = (const bf16x8*)imgB;  // units of 8 elems
    const bf16x8* __restrict__ Bp = (const bf16x8*)txtB;

    const int rowbase = strip * 64;
    bf16x8 a[4][2];
    #pragma unroll
    for (int it = 0; it < 4; ++it) {
        const int r = rowbase + it * 16 + m;
        a[it][0] = A[r * 8 + q];        // k = q*8 .. q*8+7
        a[it][1] = A[r * 8 + 4 + q];    // k = 32 + q*8 ..
    }

    const int colbase = chunk * 256 + m;      // this lane's t=0 column
    bf16x8 b0 = Bp[colbase * 8 + q];
    bf16x8 b1 = Bp[colbase * 8 + 4 + q];

    float rs[16];
    #pragma unroll
    for (int i = 0; i < 16; ++i) rs[i] = 0.f;

    const floatx4 ZERO = {0.f, 0.f, 0.f, 0.f};

    #pragma unroll 2
    for (int t = 0; t < 16; ++t) {
        // prefetch next tile's B (t=15 wraps to t=0: harmless, avoids branch)
        const int nn = colbase + (((t + 1) & 15) << 4);
        const bf16x8 pb0 = Bp[nn * 8 + q];
        const bf16x8 pb1 = Bp[nn * 8 + 4 + q];

        float csp[4];
        #pragma unroll
        for (int it = 0; it < 4; ++it) {
            floatx4 z = __builtin_amdgcn_mfma_f32_16x16x32_bf16(a[it][0], b0, ZERO, 0, 0, 0);
            floatx4 acc = __builtin_amdgcn_mfma_f32_16x16x32_bf16(a[it][1], b1, z, 0, 0, 0);
            // exp(s - M) = exp2((dot - 1) * K1)
            const float e0 = __builtin_amdgcn_exp2f(__builtin_fmaf(acc[0], K1, -K1));
            const float e1 = __builtin_amdgcn_exp2f(__builtin_fmaf(acc[1], K1, -K1));
            const float e2 = __builtin_amdgcn_exp2f(__builtin_fmaf(acc[2], K1, -K1));
            const float e3 = __builtin_amdgcn_exp2f(__builtin_fmaf(acc[3], K1, -K1));
            rs[it * 4 + 0] += e0;
            rs[it * 4 + 1] += e1;
            rs[it * 4 + 2] += e2;
            rs[it * 4 + 3] += e3;
            csp[it] = (e0 + e1) + (e2 + e3);     // depth-2 tree
        }
        float cs = (csp[0] + csp[1]) + (csp[2] + csp[3]);
        // combine the 4 quads -> col sum over all 64 rows of the strip
        cs += __shfl_xor(cs, 16, 64);
        cs += __shfl_xor(cs, 32, 64);
        if (q == 0) colPart[strip * NB + colbase + (t << 4)] = cs;  // unique writer
        b0 = pb0; b1 = pb1;
    }

    // flush row sums: reduce each rs[idx] across the 16 lanes of the quad
    #pragma unroll
    for (int idx = 0; idx < 16; ++idx) {
        float v = rs[idx];
        v += __shfl_xor(v, 1, 64);
        v += __shfl_xor(v, 2, 64);
        v += __shfl_xor(v, 4, 64);
        v += __shfl_xor(v, 8, 64);
        if (m == idx) {
            const int it = idx >> 2, r = idx & 3;
            rowPart[chunk * NB + rowbase + it * 16 + q * 4 + r] = v;  // unique writer
        }
    }
}

// --------------------------- kernel 3: finish ------------------------------
__global__ __launch_bounds__(256)
void finish_kernel(const float* __restrict__ rowPart,
                   const float* __restrict__ colPart,
                   const float* __restrict__ diag,
                   float* __restrict__ out)
{
    const int i = blockIdx.x * 256 + threadIdx.x;   // 0..8191
    float rowS = 0.f, colS = 0.f;
    #pragma unroll 4
    for (int c = 0; c < 32; ++c)  rowS += rowPart[c * NB + i];
    #pragma unroll 4
    for (int s = 0; s < 128; ++s) colS += colPart[s * NB + i];
    const float d     = diag[i];
    const float lse_r = INV_T + __builtin_amdgcn_logf(rowS) * LN2;
    const float lse_c = INV_T + __builtin_amdgcn_logf(colS) * LN2;
    const float lpr = d - lse_r;
    const float lpc = d - lse_c;
    const float p   = __builtin_amdgcn_exp2f(lpr * LOG2E);
    const float om  = 1.f - p;
    float contrib = om * om * (-lpr - lpc) * (0.5f / (float)NB);

    #pragma unroll
    for (int o = 1; o < 64; o <<= 1) contrib += __shfl_xor(contrib, o, 64);
    __shared__ float red[4];
    if ((threadIdx.x & 63) == 0) red[threadIdx.x >> 6] = contrib;
    __syncthreads();
    if (threadIdx.x == 0)
        atomicAdd(out, red[0] + red[1] + red[2] + red[3]);
}

// ---------------------------------------------------------------------------
extern "C" void kernel_launch(void* const* d_in, const int* in_sizes, int n_in,
                              void* d_out, int out_size, void* d_ws, size_t ws_size,
                              hipStream_t stream)
{
    const float* img = (const float*)d_in[0];
    const float* txt = (const float*)d_in[1];

    char* ws = (char*)d_ws;
    __hip_bfloat16* imgB = (__hip_bfloat16*)(ws);                        // 1 MB
    __hip_bfloat16* txtB = (__hip_bfloat16*)(ws + (1u << 20));           // 1 MB
    float* diag    = (float*)(ws + (2u << 20));                          // 32 KB
    float* rowPart = (float*)(ws + (2u << 20) + (1u << 16));             // 1 MB
    float* colPart = (float*)(ws + (3u << 20) + (1u << 16));             // 4 MB

    norm_kernel<<<NB / 4, 256, 0, stream>>>(img, txt, imgB, txtB, diag, (float*)d_out);
    score_kernel<<<1024, 256, 0, stream>>>(imgB, txtB, rowPart, colPart);
    finish_kernel<<<NB / 256, 256, 0, stream>>>(rowPart, colPart, diag, (float*)d_out);
}

// Round 3
// 98.292 us; speedup vs baseline: 1.0339x; 1.0028x over previous
//
#include <hip/hip_runtime.h>
#include <hip/hip_bf16.h>

// ---------------------------------------------------------------------------
// ContrastiveLoss: B=8192, D=64, fp32 inputs, scalar fp32 output.
// loss = mean_i[ w_i * (-(d_i - lse_row_i) - (d_i - lse_col_i)) ] / 2
//   w_i = (1 - exp(d_i - lse_row_i))^2,  d_i = (img_i . txt_i)/T (fp32 exact)
//   lse_row_i = M + ln( sum_j exp(s_ij - M) ),  M = 1/T  (fixed shift: |s|<=M
//   since both factors are unit vectors -> no max pass needed)
// Trick: imgB rows are pre-scaled by K1 = LOG2E/T and the MFMA C-operand is
// initialized to -K1, so the accumulator exits the matrix pipe as the exp2
// argument directly: acc = K1*dot - K1 = (s - M)*log2(e). Zero VALU fixup.
// ---------------------------------------------------------------------------

#define NB 8192
#define ND 64

constexpr float INV_T = 1.0f / 0.07f;                 // 14.2857...
constexpr float LOG2E = 1.4426950408889634f;
constexpr float LN2   = 0.6931471805599453f;
constexpr float K1    = INV_T * LOG2E;                // exp2 arg scale

typedef float  floatx4 __attribute__((ext_vector_type(4)));
typedef short  bf16x8  __attribute__((ext_vector_type(8)));

// --------------------------- kernel 1: normalize ---------------------------
// One wave per row (D=64 == wave width). Single fused butterfly reduces
// |x|^2, |t|^2, x.t together. imgB gets the K1-prescaled bf16 copy (A side),
// txtB the plain normalized bf16 (B side). Exact fp32 diagonal logit to diag.
// Also zeroes d_out (runs strictly before finish_kernel's atomicAdd).
__global__ __launch_bounds__(256)
void norm_kernel(const float* __restrict__ img, const float* __restrict__ txt,
                 __hip_bfloat16* __restrict__ imgB,
                 __hip_bfloat16* __restrict__ txtB,
                 float* __restrict__ diag,
                 float* __restrict__ out)
{
    if (blockIdx.x == 0 && threadIdx.x == 0) out[0] = 0.f;  // replaces memset node
    const int lane = threadIdx.x & 63;
    const int row  = blockIdx.x * 4 + (threadIdx.x >> 6);
    const float x = img[row * ND + lane];
    const float t = txt[row * ND + lane];
    float sx = x * x, st = t * t, sxt = x * t;
    #pragma unroll
    for (int o = 1; o < 64; o <<= 1) {
        sx  += __shfl_xor(sx,  o, 64);
        st  += __shfl_xor(st,  o, 64);
        sxt += __shfl_xor(sxt, o, 64);
    }
    const float nx_den = fmaxf(sqrtf(sx), 1e-12f);
    const float nt_den = fmaxf(sqrtf(st), 1e-12f);
    imgB[row * ND + lane] = __float2bfloat16(x / nx_den * K1);  // A pre-scaled
    txtB[row * ND + lane] = __float2bfloat16(t / nt_den);
    if (lane == 0) diag[row] = sxt / (nx_den * nt_den) * INV_T;
}

// ----------------------- kernel 2: streamed score pass ---------------------
// Wave w: strip = w>>5 (64 rows), chunk = w&31 (256 cols, 16 tiles of 16).
// A-fragments (4 row-tiles) stay in registers across the whole tile loop.
// Next tile's B-fragments are software-prefetched (branchless wraparound).
// Per 16x16 tile: 2 chained MFMAs (K=64, C init = -K1) x 4 row-tiles,
// 16 exp2 straight off the accumulator, row partials in registers,
// col partial via depth-4 tree + 2 shuffles -> unique-writer store.
// mfma_f32_16x16x32_bf16 layouts (HW-verified):
//   A: lane holds A[m=lane&15][k=(lane>>4)*8 + j], j=0..7  (8 contig bf16)
//   B: lane holds B[n=lane&15][k=(lane>>4)*8 + j]          (NT layout)
//   C/D: col = lane&15, row = (lane>>4)*4 + r
__global__ __launch_bounds__(256)
void score_kernel(const __hip_bfloat16* __restrict__ imgB,
                  const __hip_bfloat16* __restrict__ txtB,
                  float* __restrict__ rowPart,   // [32][8192]
                  float* __restrict__ colPart)   // [128][8192]
{
    const int wid   = threadIdx.x >> 6;
    const int lane  = threadIdx.x & 63;
    const int gw    = blockIdx.x * 4 + wid;   // 0..4095
    const int strip = gw >> 5;                // rows strip*64..+63
    const int chunk = gw & 31;                // cols chunk*256..+255
    const int m = lane & 15;
    const int q = lane >> 4;

    const bf16x8* __restrict__ A  = (const bf16x8*)imgB;  // units of 8 elems
    const bf16x8* __restrict__ Bp = (const bf16x8*)txtB;

    const int rowbase = strip * 64;
    bf16x8 a[4][2];
    #pragma unroll
    for (int it = 0; it < 4; ++it) {
        const int r = rowbase + it * 16 + m;
        a[it][0] = A[r * 8 + q];        // k = q*8 .. q*8+7
        a[it][1] = A[r * 8 + 4 + q];    // k = 32 + q*8 ..
    }

    const int colbase = chunk * 256 + m;      // this lane's t=0 column
    bf16x8 b0 = Bp[colbase * 8 + q];
    bf16x8 b1 = Bp[colbase * 8 + 4 + q];

    float rs[16];
    #pragma unroll
    for (int i = 0; i < 16; ++i) rs[i] = 0.f;

    const floatx4 NEGK = {-K1, -K1, -K1, -K1};   // bakes the -M shift in

    #pragma unroll 2
    for (int t = 0; t < 16; ++t) {
        // prefetch next tile's B (t=15 wraps to t=0: harmless, avoids branch)
        const int nn = colbase + (((t + 1) & 15) << 4);
        const bf16x8 pb0 = Bp[nn * 8 + q];
        const bf16x8 pb1 = Bp[nn * 8 + 4 + q];

        float csp[4];
        #pragma unroll
        for (int it = 0; it < 4; ++it) {
            floatx4 z   = __builtin_amdgcn_mfma_f32_16x16x32_bf16(a[it][0], b0, NEGK, 0, 0, 0);
            floatx4 acc = __builtin_amdgcn_mfma_f32_16x16x32_bf16(a[it][1], b1, z,    0, 0, 0);
            // acc == (s - M) * log2(e) already
            const float e0 = __builtin_amdgcn_exp2f(acc[0]);
            const float e1 = __builtin_amdgcn_exp2f(acc[1]);
            const float e2 = __builtin_amdgcn_exp2f(acc[2]);
            const float e3 = __builtin_amdgcn_exp2f(acc[3]);
            rs[it * 4 + 0] += e0;
            rs[it * 4 + 1] += e1;
            rs[it * 4 + 2] += e2;
            rs[it * 4 + 3] += e3;
            csp[it] = (e0 + e1) + (e2 + e3);     // depth-2 tree
        }
        float cs = (csp[0] + csp[1]) + (csp[2] + csp[3]);
        // combine the 4 quads -> col sum over all 64 rows of the strip
        cs += __shfl_xor(cs, 16, 64);
        cs += __shfl_xor(cs, 32, 64);
        if (q == 0) colPart[strip * NB + colbase + (t << 4)] = cs;  // unique writer
        b0 = pb0; b1 = pb1;
    }

    // flush row sums: reduce each rs[idx] across the 16 lanes of the quad
    #pragma unroll
    for (int idx = 0; idx < 16; ++idx) {
        float v = rs[idx];
        v += __shfl_xor(v, 1, 64);
        v += __shfl_xor(v, 2, 64);
        v += __shfl_xor(v, 4, 64);
        v += __shfl_xor(v, 8, 64);
        if (m == idx) {
            const int it = idx >> 2, r = idx & 3;
            rowPart[chunk * NB + rowbase + it * 16 + q * 4 + r] = v;  // unique writer
        }
    }
}

// --------------------------- kernel 3: finish ------------------------------
__global__ __launch_bounds__(256)
void finish_kernel(const float* __restrict__ rowPart,
                   const float* __restrict__ colPart,
                   const float* __restrict__ diag,
                   float* __restrict__ out)
{
    const int i = blockIdx.x * 256 + threadIdx.x;   // 0..8191
    float rowS = 0.f, colS = 0.f;
    #pragma unroll 4
    for (int c = 0; c < 32; ++c)  rowS += rowPart[c * NB + i];
    #pragma unroll 4
    for (int s = 0; s < 128; ++s) colS += colPart[s * NB + i];
    const float d     = diag[i];
    const float lse_r = INV_T + __builtin_amdgcn_logf(rowS) * LN2;
    const float lse_c = INV_T + __builtin_amdgcn_logf(colS) * LN2;
    const float lpr = d - lse_r;
    const float lpc = d - lse_c;
    const float p   = __builtin_amdgcn_exp2f(lpr * LOG2E);
    const float om  = 1.f - p;
    float contrib = om * om * (-lpr - lpc) * (0.5f / (float)NB);

    #pragma unroll
    for (int o = 1; o < 64; o <<= 1) contrib += __shfl_xor(contrib, o, 64);
    __shared__ float red[4];
    if ((threadIdx.x & 63) == 0) red[threadIdx.x >> 6] = contrib;
    __syncthreads();
    if (threadIdx.x == 0)
        atomicAdd(out, red[0] + red[1] + red[2] + red[3]);
}

// ---------------------------------------------------------------------------
extern "C" void kernel_launch(void* const* d_in, const int* in_sizes, int n_in,
                              void* d_out, int out_size, void* d_ws, size_t ws_size,
                              hipStream_t stream)
{
    const float* img = (const float*)d_in[0];
    const float* txt = (const float*)d_in[1];

    char* ws = (char*)d_ws;
    __hip_bfloat16* imgB = (__hip_bfloat16*)(ws);                        // 1 MB
    __hip_bfloat16* txtB = (__hip_bfloat16*)(ws + (1u << 20));           // 1 MB
    float* diag    = (float*)(ws + (2u << 20));                          // 32 KB
    float* rowPart = (float*)(ws + (2u << 20) + (1u << 16));             // 1 MB
    float* colPart = (float*)(ws + (3u << 20) + (1u << 16));             // 4 MB

    norm_kernel<<<NB / 4, 256, 0, stream>>>(img, txt, imgB, txtB, diag, (float*)d_out);
    score_kernel<<<1024, 256, 0, stream>>>(imgB, txtB, rowPart, colPart);
    finish_kernel<<<NB / 256, 256, 0, stream>>>(rowPart, colPart, diag, (float*)d_out);
}